// Round 1
// baseline (357.598 us; speedup 1.0000x reference)
//
#include <hip/hip_runtime.h>

// LevelLayer fused: convert -> space_emb FFN -> kNN(k=15) -> 2x GIN -> out FFN
// in ONE persistent kernel (512 blocks x 256 thr, co-resident via
// __launch_bounds__(256,2) + 75.5KB LDS => 2 blocks/CU), 3 software grid
// barriers (agent-scope atomics, 64B counter region zeroed by hipMemsetAsync).
// N=8192 nodes, 32 events x 256, LAT=64, HID=128, FIN=4, FOUT=4, SPACE=3.
// dtype (bf16 vs fp32) runtime-detected per-block from W_g1a bit patterns.
// Outputs in d_out: h[8192*64] | x_emb[8192*4] | ei[2*122880].

#define N_NODES 8192
#define NPE     256
#define KNN     15
#define LAT     64
#define HID     128
#define NK      (N_NODES*KNN)
#define NBLK    512
#define NPB     16              // nodes per block

#define CVT_TOTAL 74820
// ws byte offsets (bar counters live at [0,64))
#define OFF_CVT  64
#define OFF_HA   400000
#define OFF_HB   (OFF_HA + 2097152)
#define OFF_POS  (OFF_HB + 2097152)
#define OFF_NBR  (OFF_POS + 98304)
// float-element offsets inside cvt region
#define FO_X     0
#define FO_SE1   32768
#define FO_BSE1  33024
#define FO_SE2   33088
#define FO_BSE2  37184
#define FO_G1A   37248
#define FO_BG1A  45440
#define FO_G1B   45568
#define FO_BG1B  53760
#define FO_G2A   53824
#define FO_BG2A  62016
#define FO_G2B   62144
#define FO_BG2B  70336
#define FO_OE1   70400
#define FO_BOE1  74496
#define FO_OE2   74560
#define FO_BOE2  74816

typedef unsigned short bf16;
typedef unsigned int   u32;
typedef unsigned long long u64;

__device__ __forceinline__ float bf2f(bf16 s) {
    union { u32 u; float f; } v; v.u = ((u32)s) << 16; return v.f;
}
__device__ __forceinline__ bf16 f2bf(float f) {
    union { float f; u32 u; } v; v.f = f;
    u32 u = v.u + 0x7fffu + ((v.u >> 16) & 1u);   // RNE
    return (bf16)(u >> 16);
}

struct KArgs {
    const void* src[17];
    int off[18];
    const u32* wdet;            // d_in[7] = W_g1a raw bits
    float* cvt; float* hA; float* hB; float* pos;
    int* nbr; int* bar;
    void* out;
};

union SU {
    int red[256];
    struct { float W1[4*LAT]; float W2[LAT*LAT]; float b1[LAT]; float b2[LAT];
             float hid[4][LAT]; } sp;
    float kpos[NPE*3];
    struct { float Wa[LAT*HID]; float Wb[HID*LAT]; float ba[HID]; float bb[LAT];
             float m[8*LAT]; float own[8*LAT]; float t[8*HID]; int nb[NPB*KNN]; } gin;   // 75456 B
    struct { float W1[LAT*LAT]; float W2[LAT*4]; float b1[LAT]; float b2[4];
             float h[4][LAT]; float t[4][LAT]; } oe;
};

// one-shot per-phase grid barrier: distinct counter per phase, no sense reversal.
// Bounded spin: if co-residency were ever violated we produce a clean wrong
// answer (bench fail) instead of a hang.
__device__ __forceinline__ void gridbar(int* c, int nb) {
    __syncthreads();
    if (threadIdx.x == 0) {
        __threadfence();        // release: drain this block's global writes
        __hip_atomic_fetch_add(c, 1, __ATOMIC_ACQ_REL, __HIP_MEMORY_SCOPE_AGENT);
        int guard = 0;
        while (__hip_atomic_load(c, __ATOMIC_ACQUIRE, __HIP_MEMORY_SCOPE_AGENT) < nb) {
            __builtin_amdgcn_s_sleep(2);
            if (++guard > (1 << 22)) break;     // fail-safe, ~0.25 s worst case
        }
        __threadfence();        // acquire: invalidate stale cache lines
    }
    __syncthreads();
}

__device__ __forceinline__ void gin_layer(SU& S, const KArgs& a,
        const float* __restrict__ hin, float* __restrict__ hout,
        const float* __restrict__ Wa, const float* __restrict__ ba,
        const float* __restrict__ Wb, const float* __restrict__ bb)
{
    const int tid = threadIdx.x, blk = blockIdx.x;
    {   // stage weights as float4 (L2-hot: 64 KB shared by all blocks)
        const float4* ga = (const float4*)Wa;
        const float4* gb = (const float4*)Wb;
        float4* sa = (float4*)S.gin.Wa;
        float4* sb = (float4*)S.gin.Wb;
        for (int i = tid; i < LAT*HID/4; i += 256) { sa[i] = ga[i]; sb[i] = gb[i]; }
    }
    if (tid < HID) S.gin.ba[tid] = ba[tid];
    if (tid < LAT) S.gin.bb[tid] = bb[tid];
    if (tid < NPB*KNN) S.gin.nb[tid] = a.nbr[blk*NPB*KNN + tid] & (N_NODES - 1);
    __syncthreads();
    for (int g = 0; g < 2; ++g) {               // two 8-node groups
        const int base = blk*NPB + g*8;
        // phase 1: m = own + sum of 15 neighbors
        #pragma unroll
        for (int p = 0; p < 2; p++) {
            const int e = tid + p*256, n = e >> 6, f = e & 63, gi = base + n;
            const float own = hin[gi*LAT + f];
            float acc = own;
            #pragma unroll
            for (int k = 0; k < KNN; k++) acc += hin[S.gin.nb[(g*8+n)*KNN + k]*LAT + f];
            S.gin.m[e] = acc; S.gin.own[e] = own;
        }
        __syncthreads();
        // phase 2: t = relu(m @ Wa + ba); thread = (node, 4 consecutive u)
        {
            const int n = tid >> 5, ug = (tid & 31)*4;
            float a0 = S.gin.ba[ug], a1 = S.gin.ba[ug+1], a2 = S.gin.ba[ug+2], a3 = S.gin.ba[ug+3];
            for (int f = 0; f < LAT; f++) {
                const float mv = S.gin.m[n*LAT + f];
                const float4 w = *(const float4*)&S.gin.Wa[f*HID + ug];
                a0 = fmaf(mv, w.x, a0); a1 = fmaf(mv, w.y, a1);
                a2 = fmaf(mv, w.z, a2); a3 = fmaf(mv, w.w, a3);
            }
            S.gin.t[n*HID+ug]   = a0 > 0.f ? a0 : 0.f;
            S.gin.t[n*HID+ug+1] = a1 > 0.f ? a1 : 0.f;
            S.gin.t[n*HID+ug+2] = a2 > 0.f ? a2 : 0.f;
            S.gin.t[n*HID+ug+3] = a3 > 0.f ? a3 : 0.f;
        }
        __syncthreads();
        // phase 3: out = own + t @ Wb + bb; thread = (node, 2 consecutive f)
        {
            const int n = tid >> 5, fp = (tid & 31)*2, gi = base + n;
            float a0 = S.gin.bb[fp], a1 = S.gin.bb[fp+1];
            for (int u = 0; u < HID; u++) {
                const float tv = S.gin.t[n*HID + u];
                const float2 w = *(const float2*)&S.gin.Wb[u*LAT + fp];
                a0 = fmaf(tv, w.x, a0); a1 = fmaf(tv, w.y, a1);
            }
            float2 o;
            o.x = S.gin.own[n*LAT+fp]   + a0;
            o.y = S.gin.own[n*LAT+fp+1] + a1;
            *(float2*)&hout[gi*LAT + fp] = o;
        }
        __syncthreads();
    }
}

__global__ __launch_bounds__(256, 2) void k_fused(KArgs a)
{
    __shared__ __align__(16) SU S;
    __shared__ int sflag;
    const int tid = threadIdx.x, blk = blockIdx.x;

    // ---- A0: dtype detect (every block; identical result, L2-hot 16 KB scan)
    {
        int c = 0;
        for (int i = tid; i < 4096; i += 256) {
            const u32 x = a.wdet[i];
            c += ((x >> 7)  & 0xffu) >= 0xC8u;   // low half as bf16: |v| >= 2^73
            c += ((x >> 23) & 0xffu) >= 0xC8u;   // high half
        }
        S.red[tid] = c;
        __syncthreads();
        for (int s = 128; s > 0; s >>= 1) {
            if (tid < s) S.red[tid] += S.red[tid + s];
            __syncthreads();
        }
        if (tid == 0) sflag = (S.red[0] > 64) ? 1 : 0;   // 1 = inputs are fp32
        __syncthreads();
    }
    const int flag = sflag;

    // ---- A1: convert all floating inputs to canonical fp32 (1 elem/thread)
    {
        const int i = blk*256 + tid;
        if (i < CVT_TOTAL) {
            int t = 0;
            while (i >= a.off[t + 1]) ++t;
            const int l = i - a.off[t];
            a.cvt[i] = flag ? ((const float*)a.src[t])[l]
                            : bf2f(((const bf16*)a.src[t])[l]);
        }
    }
    gridbar(a.bar + 0, NBLK);       // weights visible everywhere

    // ---- B: space_emb h = leaky(x@W1+b1)@W2+b2 ; 16 nodes/block
    {
        const float* __restrict__ x  = a.cvt + FO_X;
        const float* __restrict__ W1 = a.cvt + FO_SE1;
        const float* __restrict__ b1 = a.cvt + FO_BSE1;
        const float* __restrict__ W2 = a.cvt + FO_SE2;
        const float* __restrict__ b2 = a.cvt + FO_BSE2;
        for (int i = tid; i < 4*LAT; i += 256)   S.sp.W1[i] = W1[i];
        for (int i = tid; i < LAT*LAT; i += 256) S.sp.W2[i] = W2[i];
        if (tid < LAT) { S.sp.b1[tid] = b1[tid]; S.sp.b2[tid] = b2[tid]; }
        __syncthreads();
        const int ln = tid >> 6, f = tid & 63;
        for (int g = 0; g < 4; ++g) {
            const int node = blk*NPB + g*4 + ln;
            float acc = S.sp.b1[f];
            #pragma unroll
            for (int i = 0; i < 4; i++) acc = fmaf(x[node*4 + i], S.sp.W1[i*LAT + f], acc);
            acc = acc > 0.f ? acc : 0.01f*acc;          // leaky
            S.sp.hid[ln][f] = acc;
            __syncthreads();
            float a2 = S.sp.b2[f];
            for (int j = 0; j < LAT; j++) a2 = fmaf(S.sp.hid[ln][j], S.sp.W2[j*LAT + f], a2);
            a.hA[node*LAT + f] = a2;
            if (f < 3) a.pos[node*3 + f] = a2;
            __syncthreads();
        }
    }
    gridbar(a.bar + 1, NBLK);       // pos + hA of ALL blocks visible

    // ---- C: kNN, one wave per node, 4 sequential nodes per wave
    {
        const int base = blk*NPB;
        const int eb = base & ~(NPE - 1);           // event base
        for (int i = tid; i < NPE*3; i += 256) S.kpos[i] = a.pos[(size_t)eb*3 + i];
        __syncthreads();
        const int wave = tid >> 6, lane = tid & 63;
        const int EI0 = N_NODES*LAT + N_NODES*4;
        for (int t = 0; t < 4; ++t) {
            const int n  = base + wave*4 + t;
            const int nl = n - eb;
            const float px = S.kpos[nl*3], py = S.kpos[nl*3+1], pz = S.kpos[nl*3+2];
            u64 key[4];
            #pragma unroll
            for (int c = 0; c < 4; c++) {
                const int j = 64*c + lane;
                const float dx = px - S.kpos[j*3], dy = py - S.kpos[j*3+1], dz = pz - S.kpos[j*3+2];
                // match numpy fp32 ((x^2 + y^2) + z^2), contraction suppressed
                float dd = __fmul_rn(dx, dx);
                dd = __fadd_rn(dd, __fmul_rn(dy, dy));
                dd = __fadd_rn(dd, __fmul_rn(dz, dz));
                key[c] = ((u64)__float_as_uint(dd) << 32) | (u32)j;
                if (j == nl) key[c] = ~0ull;         // exclude self
            }
            u64 lmin = key[0] < key[1] ? key[0] : key[1];
            { u64 q = key[2] < key[3] ? key[2] : key[3]; lmin = q < lmin ? q : lmin; }
            int myj = 0;                              // lane k keeps the k-th winner
            #pragma unroll
            for (int k = 0; k < KNN; k++) {
                u64 m = lmin;
                #pragma unroll
                for (int s = 32; s >= 1; s >>= 1) {  // butterfly min over 64 lanes
                    const u64 o = __shfl_xor(m, s, 64);
                    m = o < m ? o : m;
                }
                if (lane == k) myj = (int)(u32)m;
                #pragma unroll
                for (int c = 0; c < 4; c++) if (key[c] == m) key[c] = ~0ull;
                lmin = key[0] < key[1] ? key[0] : key[1];
                { u64 q = key[2] < key[3] ? key[2] : key[3]; lmin = q < lmin ? q : lmin; }
            }
            if (lane < KNN) {
                const int gj = eb + myj;
                a.nbr[n*KNN + lane] = gj;
                if (flag) {
                    float* o = (float*)a.out;
                    o[EI0 + n*KNN + lane]      = (float)gj;
                    o[EI0 + NK + n*KNN + lane] = (float)n;
                } else {
                    bf16* o = (bf16*)a.out;
                    o[EI0 + n*KNN + lane]      = f2bf((float)gj);
                    o[EI0 + NK + n*KNN + lane] = f2bf((float)n);
                }
            }
        }
    }
    // NO grid barrier: each block consumes only its OWN nodes' nbr lists,
    // and neighbor h (hA) was already fenced by gridbar #1.
    __syncthreads();

    // ---- D: GIN layer 1 (hA -> hB)
    gin_layer(S, a, a.hA, a.hB,
              a.cvt + FO_G1A, a.cvt + FO_BG1A, a.cvt + FO_G1B, a.cvt + FO_BG1B);
    gridbar(a.bar + 2, NBLK);       // neighbors' hB visible

    // ---- E: GIN layer 2 (hB -> hA)
    gin_layer(S, a, a.hB, a.hA,
              a.cvt + FO_G2A, a.cvt + FO_BG2A, a.cvt + FO_G2B, a.cvt + FO_BG2B);
    // NO grid barrier: out phase reads only this block's own 16 nodes of hA.

    // ---- F: out_emb + final stores, 16 nodes/block
    {
        const float* __restrict__ W1 = a.cvt + FO_OE1;
        const float* __restrict__ b1 = a.cvt + FO_BOE1;
        const float* __restrict__ W2 = a.cvt + FO_OE2;
        const float* __restrict__ b2 = a.cvt + FO_BOE2;
        for (int i = tid; i < LAT*LAT; i += 256) S.oe.W1[i] = W1[i];
        if (tid < LAT*4) S.oe.W2[tid] = W2[tid];
        if (tid < LAT) S.oe.b1[tid] = b1[tid];
        if (tid < 4)   S.oe.b2[tid] = b2[tid];
        __syncthreads();
        const int ln = tid >> 6, f = tid & 63;
        const bool f32out = (flag != 0);
        for (int g = 0; g < 4; ++g) {
            const int node = blk*NPB + g*4 + ln;
            const float hv = a.hA[node*LAT + f];
            S.oe.h[ln][f] = hv;
            if (f32out) ((float*)a.out)[node*LAT + f] = hv;     // output 0: final h
            else        ((bf16*)a.out)[node*LAT + f] = f2bf(hv);
            __syncthreads();
            float acc = S.oe.b1[f];
            for (int j = 0; j < LAT; j++) acc = fmaf(S.oe.h[ln][j], S.oe.W1[j*LAT + f], acc);
            acc = acc > 0.f ? acc : 0.01f*acc;          // leaky
            S.oe.t[ln][f] = acc;
            __syncthreads();
            if (f < 4) {
                float av = S.oe.b2[f];
                for (int j = 0; j < LAT; j++) av = fmaf(S.oe.t[ln][j], S.oe.W2[j*4 + f], av);
                const int xo = N_NODES*LAT + node*4 + f;        // output 1: x_emb
                if (f32out) ((float*)a.out)[xo] = av;
                else        ((bf16*)a.out)[xo] = f2bf(av);
            }
            __syncthreads();
        }
    }
}

extern "C" void kernel_launch(void* const* d_in, const int* in_sizes, int n_in,
                              void* d_out, int out_size, void* d_ws, size_t ws_size,
                              hipStream_t stream)
{
    (void)in_sizes; (void)n_in; (void)out_size; (void)ws_size;
    char* ws = (char*)d_ws;

    KArgs a;
    const int idx[17] = {0, 3, 4, 5, 6, 7, 8, 9, 10, 11, 12, 13, 14, 15, 16, 17, 18};
    const int off[18] = {FO_X, FO_SE1, FO_BSE1, FO_SE2, FO_BSE2, FO_G1A, FO_BG1A,
                         FO_G1B, FO_BG1B, FO_G2A, FO_BG2A, FO_G2B, FO_BG2B,
                         FO_OE1, FO_BOE1, FO_OE2, FO_BOE2, CVT_TOTAL};
    for (int i = 0; i < 17; i++) a.src[i] = d_in[idx[i]];
    for (int i = 0; i < 18; i++) a.off[i] = off[i];
    a.wdet = (const u32*)d_in[7];
    a.cvt  = (float*)(ws + OFF_CVT);
    a.hA   = (float*)(ws + OFF_HA);
    a.hB   = (float*)(ws + OFF_HB);
    a.pos  = (float*)(ws + OFF_POS);
    a.nbr  = (int*)(ws + OFF_NBR);
    a.bar  = (int*)ws;
    a.out  = d_out;

    hipMemsetAsync(d_ws, 0, 64, stream);          // zero barrier counters (captured)
    k_fused<<<dim3(NBLK), dim3(256), 0, stream>>>(a);
}

// Round 2
// 236.067 us; speedup vs baseline: 1.5148x; 1.5148x over previous
//
#include <hip/hip_runtime.h>

// LevelLayer fully fused, one persistent kernel, 1024 blocks x 256 thr
// (4 blocks/CU via ~11KB LDS + __launch_bounds__(256,4) => 16 waves/CU).
// Phases: detect -> space FFN -> [GRIDBAR] -> kNN -> GIN1 -> [GRIDBAR] ->
//         GIN2 -> out FFN.  Weights are read inline from d_in (bf16 or fp32,
//         runtime-detected) -- no convert pass, no LDS weight staging.
// Grid barrier: release-fence + relaxed fetch_add arrival; last arriver
// release-stores a flag on a separate line; spinners poll the flag with
// RELAXED agent loads (no per-poll buffer_inv), single acquire fence on exit.
// Outputs in d_out: h[8192*64] | x_emb[8192*4] | ei[2*122880].

#define N_NODES 8192
#define NPE     256
#define KNN     15
#define LAT     64
#define HID     128
#define NK      (N_NODES*KNN)
#define NBLK    1024
#define NPB     8
#define EI0     (N_NODES*LAT + N_NODES*4)

// ws byte offsets (barrier counters/flags live in [0,512))
#define OFF_HA  4096
#define OFF_HB  (OFF_HA + N_NODES*LAT*4)
#define OFF_POS (OFF_HB + N_NODES*LAT*4)

typedef unsigned short bf16;
typedef unsigned int   u32;
typedef unsigned long long u64;

__device__ __forceinline__ float bf2f(bf16 s) {
    union { u32 u; float f; } v; v.u = ((u32)s) << 16; return v.f;
}
__device__ __forceinline__ bf16 f2bf(float f) {
    union { float f; u32 u; } v; v.f = f;
    u32 u = v.u + 0x7fffu + ((v.u >> 16) & 1u);   // RNE
    return (bf16)(u >> 16);
}
__device__ __forceinline__ float ldf(const void* p, int i, int f32) {
    return f32 ? ((const float*)p)[i] : bf2f(((const bf16*)p)[i]);
}

struct KArgs {
    const void* x;
    const void* se1; const void* bse1; const void* se2; const void* bse2;
    const void* g1a; const void* bg1a; const void* g1b; const void* bg1b;
    const void* g2a; const void* bg2a; const void* g2b; const void* bg2b;
    const void* oe1; const void* boe1; const void* oe2; const void* boe2;
    const u32* wdet;                 // d_in[7] = W_g1a raw bits (>=16KB both dtypes)
    float* hA; float* hB; float* pos; int* bar;
    void* out;
};

struct Shm {
    union {
        int   red[256];                                        // detect
        float hid[NPB][LAT];                                   // space mid
        float kpos[NPE * 3];                                   // knn
        struct { float m[NPB*LAT]; float own[NPB*LAT]; float t[NPB*HID]; } g;  // gin
        float st[NPB*LAT];                                     // out mid
    } u;                                                       // max 8 KB
    int   snb[NPB*KNN];   // this block's neighbor lists (global ids)
    float sh[NPB*LAT];    // gin2 output, consumed by out FFN
    int   flag;
};

// Flag-based one-shot grid barrier. Relaxed polling (agent-coherent load,
// no per-poll cache invalidate); one acquire fence on exit. Bounded spin:
// broken co-residency -> clean wrong answer, never a hang.
__device__ __forceinline__ void gridbar(int* cnt, int* flg) {
    __syncthreads();
    if (threadIdx.x == 0) {
        __builtin_amdgcn_fence(__ATOMIC_RELEASE, "agent");     // wb dirty L2 once
        const int old = __hip_atomic_fetch_add(cnt, 1, __ATOMIC_RELAXED,
                                               __HIP_MEMORY_SCOPE_AGENT);
        if (old == NBLK - 1) {
            __hip_atomic_store(flg, 1, __ATOMIC_RELEASE, __HIP_MEMORY_SCOPE_AGENT);
        } else {
            int guard = 0;
            while (__hip_atomic_load(flg, __ATOMIC_RELAXED,
                                     __HIP_MEMORY_SCOPE_AGENT) == 0) {
                __builtin_amdgcn_s_sleep(4);
                if (++guard > (1 << 19)) break;                // ~65 ms fail-safe
            }
        }
        __builtin_amdgcn_fence(__ATOMIC_ACQUIRE, "agent");     // inv stale lines once
    }
    __syncthreads();
}

// GIN layer: hout = hin + mlp(hin + sum_nbr hin). Weights from global (L2-hot,
// broadcast within wave), inline bf16 conversion. LAST: keep result in S.sh and
// write final-h output instead of hB.
template<bool LAST>
__device__ __forceinline__ void gin_layer(Shm& S, int base, int f32,
        const float* __restrict__ hin, float* __restrict__ hout,
        const void* Wa, const void* ba, const void* Wb, const void* bb,
        void* out)
{
    const int tid = threadIdx.x;
    // phase 1: m = own + sum of 15 neighbors (rows coalesced, event-local L2/L3)
    #pragma unroll
    for (int p = 0; p < 2; p++) {
        const int e = tid + p*256, n = e >> 6, f = e & 63, gi = base + n;
        const float own = hin[gi*LAT + f];
        float acc = own;
        #pragma unroll
        for (int k = 0; k < KNN; k++) acc += hin[S.snb[n*KNN + k]*LAT + f];
        S.u.g.m[e] = acc; S.u.g.own[e] = own;
    }
    __syncthreads();
    // phase 2: t = relu(m @ Wa + ba); thread = (node, 4 consecutive u)
    {
        const int n = tid >> 5, ug = (tid & 31)*4;
        float a0 = ldf(ba, ug, f32),   a1 = ldf(ba, ug+1, f32);
        float a2 = ldf(ba, ug+2, f32), a3 = ldf(ba, ug+3, f32);
        if (f32) {
            const float* W = (const float*)Wa;
            #pragma unroll 8
            for (int f = 0; f < LAT; f++) {
                const float mv = S.u.g.m[n*LAT + f];
                const float4 w = *(const float4*)&W[f*HID + ug];
                a0 = fmaf(mv, w.x, a0); a1 = fmaf(mv, w.y, a1);
                a2 = fmaf(mv, w.z, a2); a3 = fmaf(mv, w.w, a3);
            }
        } else {
            const bf16* W = (const bf16*)Wa;
            #pragma unroll 8
            for (int f = 0; f < LAT; f++) {
                const float mv = S.u.g.m[n*LAT + f];
                const ushort4 w = *(const ushort4*)&W[f*HID + ug];
                a0 = fmaf(mv, bf2f(w.x), a0); a1 = fmaf(mv, bf2f(w.y), a1);
                a2 = fmaf(mv, bf2f(w.z), a2); a3 = fmaf(mv, bf2f(w.w), a3);
            }
        }
        S.u.g.t[n*HID + ug]     = a0 > 0.f ? a0 : 0.f;
        S.u.g.t[n*HID + ug + 1] = a1 > 0.f ? a1 : 0.f;
        S.u.g.t[n*HID + ug + 2] = a2 > 0.f ? a2 : 0.f;
        S.u.g.t[n*HID + ug + 3] = a3 > 0.f ? a3 : 0.f;
    }
    __syncthreads();
    // phase 3: out = own + t @ Wb + bb; thread = (node, 2 consecutive f)
    {
        const int n = tid >> 5, fp = (tid & 31)*2, gi = base + n;
        float a0 = ldf(bb, fp, f32), a1 = ldf(bb, fp+1, f32);
        if (f32) {
            const float* W = (const float*)Wb;
            #pragma unroll 8
            for (int u = 0; u < HID; u++) {
                const float tv = S.u.g.t[n*HID + u];
                const float2 w = *(const float2*)&W[u*LAT + fp];
                a0 = fmaf(tv, w.x, a0); a1 = fmaf(tv, w.y, a1);
            }
        } else {
            const bf16* W = (const bf16*)Wb;
            #pragma unroll 8
            for (int u = 0; u < HID; u++) {
                const float tv = S.u.g.t[n*HID + u];
                const ushort2 w = *(const ushort2*)&W[u*LAT + fp];
                a0 = fmaf(tv, bf2f(w.x), a0); a1 = fmaf(tv, bf2f(w.y), a1);
            }
        }
        const float o0 = S.u.g.own[n*LAT + fp]     + a0;
        const float o1 = S.u.g.own[n*LAT + fp + 1] + a1;
        if (!LAST) {
            float2 o; o.x = o0; o.y = o1;
            *(float2*)&hout[gi*LAT + fp] = o;
        } else {
            S.sh[n*LAT + fp] = o0; S.sh[n*LAT + fp + 1] = o1;
            if (f32) {
                ((float*)out)[gi*LAT + fp]     = o0;        // output 0: final h
                ((float*)out)[gi*LAT + fp + 1] = o1;
            } else {
                const u32 pk = (u32)f2bf(o0) | ((u32)f2bf(o1) << 16);
                *(u32*)((bf16*)out + gi*LAT + fp) = pk;
            }
        }
    }
    __syncthreads();
}

__global__ __launch_bounds__(256, 4) void k_fused(KArgs a)
{
    __shared__ Shm S;
    const int tid = threadIdx.x, blk = blockIdx.x;
    const int base = blk * NPB;

    // ---- P0: dtype detect (16 KB scan of W_g1a; L2-hot after first blocks)
    {
        int c = 0;
        for (int i = tid; i < 4096; i += 256) {
            const u32 x = a.wdet[i];
            c += ((x >> 7)  & 0xffu) >= 0xC8u;   // low half as bf16: |v| >= 2^73
            c += ((x >> 23) & 0xffu) >= 0xC8u;   // high half
        }
        S.u.red[tid] = c;
        __syncthreads();
        for (int s = 128; s > 0; s >>= 1) {
            if (tid < s) S.u.red[tid] += S.u.red[tid + s];
            __syncthreads();
        }
        if (tid == 0) S.flag = (S.u.red[0] > 64) ? 1 : 0;   // 1 = fp32 inputs
        __syncthreads();
    }
    const int f32 = S.flag;

    // ---- P1: space_emb  h = leaky(x@W1+b1)@W2+b2  (weights inline from d_in)
    {
        #pragma unroll
        for (int p = 0; p < 2; p++) {
            const int e = tid + p*256, n = e >> 6, f = e & 63, node = base + n;
            float acc = ldf(a.bse1, f, f32);
            #pragma unroll
            for (int i = 0; i < 4; i++)
                acc = fmaf(ldf(a.x, node*4 + i, f32), ldf(a.se1, i*LAT + f, f32), acc);
            acc = acc > 0.f ? acc : 0.01f*acc;              // leaky
            S.u.hid[n][f] = acc;
        }
        __syncthreads();
        #pragma unroll
        for (int p = 0; p < 2; p++) {
            const int e = tid + p*256, n = e >> 6, f = e & 63, node = base + n;
            float acc = ldf(a.bse2, f, f32);
            if (f32) {
                const float* W = (const float*)a.se2;
                #pragma unroll 8
                for (int j = 0; j < LAT; j++) acc = fmaf(S.u.hid[n][j], W[j*LAT + f], acc);
            } else {
                const bf16* W = (const bf16*)a.se2;
                #pragma unroll 8
                for (int j = 0; j < LAT; j++) acc = fmaf(S.u.hid[n][j], bf2f(W[j*LAT + f]), acc);
            }
            a.hA[node*LAT + f] = acc;
            if (f < 3) a.pos[node*3 + f] = acc;
        }
    }
    gridbar(a.bar + 0, a.bar + 32);          // pos + hA of ALL blocks visible

    // ---- P2: kNN; one wave per node, 2 nodes per wave; nbr kept in LDS
    {
        const int eb = base & ~(NPE - 1);
        for (int i = tid; i < NPE*3; i += 256) S.u.kpos[i] = a.pos[(size_t)eb*3 + i];
        __syncthreads();
        const int wave = tid >> 6, lane = tid & 63;
        #pragma unroll
        for (int t = 0; t < 2; ++t) {
            const int n  = base + wave*2 + t;
            const int nl = n - eb;
            const float px = S.u.kpos[nl*3], py = S.u.kpos[nl*3+1], pz = S.u.kpos[nl*3+2];
            u64 key[4];
            #pragma unroll
            for (int c = 0; c < 4; c++) {
                const int j = 64*c + lane;
                const float dx = px - S.u.kpos[j*3], dy = py - S.u.kpos[j*3+1],
                            dz = pz - S.u.kpos[j*3+2];
                // match numpy fp32 ((x^2 + y^2) + z^2), contraction suppressed
                float dd = __fmul_rn(dx, dx);
                dd = __fadd_rn(dd, __fmul_rn(dy, dy));
                dd = __fadd_rn(dd, __fmul_rn(dz, dz));
                key[c] = ((u64)__float_as_uint(dd) << 32) | (u32)j;
                if (j == nl) key[c] = ~0ull;                 // exclude self
            }
            u64 lmin = key[0] < key[1] ? key[0] : key[1];
            { u64 q = key[2] < key[3] ? key[2] : key[3]; lmin = q < lmin ? q : lmin; }
            int myj = 0;                                     // lane k keeps k-th winner
            #pragma unroll
            for (int k = 0; k < KNN; k++) {
                u64 m = lmin;
                #pragma unroll
                for (int s = 32; s >= 1; s >>= 1) {          // butterfly min, 64 lanes
                    const u64 o = __shfl_xor(m, s, 64);
                    m = o < m ? o : m;
                }
                if (lane == k) myj = (int)(u32)m;
                #pragma unroll
                for (int c = 0; c < 4; c++) if (key[c] == m) key[c] = ~0ull;
                lmin = key[0] < key[1] ? key[0] : key[1];
                { u64 q = key[2] < key[3] ? key[2] : key[3]; lmin = q < lmin ? q : lmin; }
            }
            if (lane < KNN) {
                const int gj = eb + myj;
                S.snb[(n - base)*KNN + lane] = gj;
                if (f32) {
                    float* o = (float*)a.out;
                    o[EI0 + n*KNN + lane]      = (float)gj;  // output 2: ei
                    o[EI0 + NK + n*KNN + lane] = (float)n;
                } else {
                    bf16* o = (bf16*)a.out;
                    o[EI0 + n*KNN + lane]      = f2bf((float)gj);
                    o[EI0 + NK + n*KNN + lane] = f2bf((float)n);
                }
            }
        }
        __syncthreads();
    }

    // ---- P3: GIN layer 1 (hA -> hB)
    gin_layer<false>(S, base, f32, a.hA, a.hB,
                     a.g1a, a.bg1a, a.g1b, a.bg1b, nullptr);
    gridbar(a.bar + 64, a.bar + 96);         // neighbors' hB visible

    // ---- P4: GIN layer 2 (hB -> LDS sh + d_out h)
    gin_layer<true>(S, base, f32, a.hB, nullptr,
                    a.g2a, a.bg2a, a.g2b, a.bg2b, a.out);

    // ---- P5: out_emb FFN from LDS sh (block-local, no barrier needed)
    {
        #pragma unroll
        for (int p = 0; p < 2; p++) {
            const int e = tid + p*256, n = e >> 6, f = e & 63;
            float acc = ldf(a.boe1, f, f32);
            if (f32) {
                const float* W = (const float*)a.oe1;
                #pragma unroll 8
                for (int j = 0; j < LAT; j++) acc = fmaf(S.sh[n*LAT + j], W[j*LAT + f], acc);
            } else {
                const bf16* W = (const bf16*)a.oe1;
                #pragma unroll 8
                for (int j = 0; j < LAT; j++) acc = fmaf(S.sh[n*LAT + j], bf2f(W[j*LAT + f]), acc);
            }
            acc = acc > 0.f ? acc : 0.01f*acc;              // leaky
            S.u.st[e] = acc;                                 // e == n*LAT + f
        }
        __syncthreads();
        if (tid < NPB*4) {
            const int n = tid >> 2, f = tid & 3;
            float acc = ldf(a.boe2, f, f32);
            for (int j = 0; j < LAT; j++)
                acc = fmaf(S.u.st[n*LAT + j], ldf(a.oe2, j*4 + f, f32), acc);
            const int xo = N_NODES*LAT + (base + n)*4 + f;   // output 1: x_emb
            if (f32) ((float*)a.out)[xo] = acc;
            else     ((bf16*)a.out)[xo] = f2bf(acc);
        }
    }
}

extern "C" void kernel_launch(void* const* d_in, const int* in_sizes, int n_in,
                              void* d_out, int out_size, void* d_ws, size_t ws_size,
                              hipStream_t stream)
{
    (void)in_sizes; (void)n_in; (void)out_size; (void)ws_size;
    char* ws = (char*)d_ws;

    KArgs a;
    a.x   = d_in[0];
    a.se1 = d_in[3];  a.bse1 = d_in[4];  a.se2 = d_in[5];  a.bse2 = d_in[6];
    a.g1a = d_in[7];  a.bg1a = d_in[8];  a.g1b = d_in[9];  a.bg1b = d_in[10];
    a.g2a = d_in[11]; a.bg2a = d_in[12]; a.g2b = d_in[13]; a.bg2b = d_in[14];
    a.oe1 = d_in[15]; a.boe1 = d_in[16]; a.oe2 = d_in[17]; a.boe2 = d_in[18];
    a.wdet = (const u32*)d_in[7];
    a.hA  = (float*)(ws + OFF_HA);
    a.hB  = (float*)(ws + OFF_HB);
    a.pos = (float*)(ws + OFF_POS);
    a.bar = (int*)ws;
    a.out = d_out;

    hipMemsetAsync(d_ws, 0, 512, stream);     // zero barrier counters (captured)
    k_fused<<<dim3(NBLK), dim3(256), 0, stream>>>(a);
}

// Round 3
// 160.616 us; speedup vs baseline: 2.2264x; 1.4698x over previous
//
#include <hip/hip_runtime.h>

// LevelLayer fully fused, one persistent kernel, 1024 blocks x 256 thr
// (4 blocks/CU via ~11KB LDS + __launch_bounds__(256,4) => 16 waves/CU).
// Phases: detect -> space FFN -> [BAR A] -> kNN -> GIN1 -> [BAR B] ->
//         GIN2 -> out FFN.
// Cross-block data (pos/hA/hB) is written with AGENT-scope relaxed atomic
// stores (cache-bypassing, complete at coherence point) => the grid barrier
// needs NO L2 writeback/invalidate fences. Readers use normal loads: the
// lines were never locally cached (bypassed on write, first touch after the
// barrier), so they miss to L3 and see fresh data.
// Barrier: 32-leaf + root counter tree, 32 spread flag lines, relaxed polling.
// FFN matmuls are register-blocked: each weight load feeds 2-4 node
// accumulators; weight streams are contiguous 256B/wave; LDS reads are
// broadcasts (conflict-free).
// Outputs in d_out: h[8192*64] | x_emb[8192*4] | ei[2*122880].

#define N_NODES 8192
#define NPE     256
#define KNN     15
#define LAT     64
#define HID     128
#define NK      (N_NODES*KNN)
#define NBLK    1024
#define NPB     8
#define EI0     (N_NODES*LAT + N_NODES*4)

// barrier region (zeroed by hipMemsetAsync each launch)
#define BARA_LEAF 0
#define BARA_ROOT 2048
#define BARA_FLAG 4096
#define BARB_LEAF 8192
#define BARB_ROOT 10240
#define BARB_FLAG 12288
#define BAR_BYTES 16384

#define OFF_HA  BAR_BYTES
#define OFF_HB  (OFF_HA + N_NODES*LAT*4)
#define OFF_POS (OFF_HB + N_NODES*LAT*4)

typedef unsigned short bf16;
typedef unsigned int   u32;
typedef unsigned long long u64;

__device__ __forceinline__ float bf2f(bf16 s) {
    union { u32 u; float f; } v; v.u = ((u32)s) << 16; return v.f;
}
__device__ __forceinline__ bf16 f2bf(float f) {
    union { float f; u32 u; } v; v.f = f;
    u32 u = v.u + 0x7fffu + ((v.u >> 16) & 1u);   // RNE
    return (bf16)(u >> 16);
}
__device__ __forceinline__ float ldf(const void* p, int i, int f32) {
    return f32 ? ((const float*)p)[i] : bf2f(((const bf16*)p)[i]);
}
// agent-scope relaxed atomic store: bypasses local L1/L2, completes at the
// cross-XCD coherence point. vmcnt(0) after these == globally visible.
__device__ __forceinline__ void st_coh(float* p, float v) {
    __hip_atomic_store(p, v, __ATOMIC_RELAXED, __HIP_MEMORY_SCOPE_AGENT);
}

struct KArgs {
    const void* x;
    const void* se1; const void* bse1; const void* se2; const void* bse2;
    const void* g1a; const void* bg1a; const void* g1b; const void* bg1b;
    const void* g2a; const void* bg2a; const void* g2b; const void* bg2b;
    const void* oe1; const void* boe1; const void* oe2; const void* boe2;
    const u32* wdet;                 // d_in[7] = W_g1a raw bits
    float* hA; float* hB; float* pos; int* bar;
    void* out;
};

struct Shm {
    union {
        int   red[256];                                        // detect
        float hid[NPB][LAT];                                   // space mid
        float kpos[NPE * 3];                                   // knn
        struct { float m[NPB*LAT]; float own[NPB*LAT]; float t[NPB*HID]; } g;  // gin
        float st[NPB*LAT];                                     // out mid
    } u;                                                       // 8 KB
    int   snb[NPB*KNN];
    float sh[NPB*LAT];    // gin2 output, consumed by out FFN
    int   flag;
};

// Fence-free tree grid barrier. Data visibility comes from st_coh stores
// (already at coherence point) + vmcnt(0) before arrival. No wbL2/invL2.
// Bounded spin: broken co-residency -> clean wrong answer, never a hang.
__device__ __forceinline__ void gridbar(int* leaf, int* root, int* flags) {
    asm volatile("s_waitcnt vmcnt(0)" ::: "memory");   // all waves: stores acked
    __syncthreads();
    if (threadIdx.x == 0) {
        const int l = blockIdx.x & 31;
        if (__hip_atomic_fetch_add(leaf + l*16, 1, __ATOMIC_RELAXED,
                                   __HIP_MEMORY_SCOPE_AGENT) == 31) {
            if (__hip_atomic_fetch_add(root, 1, __ATOMIC_RELAXED,
                                       __HIP_MEMORY_SCOPE_AGENT) == 31) {
                #pragma unroll
                for (int i = 0; i < 32; i++)
                    __hip_atomic_store(flags + i*16, 1, __ATOMIC_RELAXED,
                                       __HIP_MEMORY_SCOPE_AGENT);
            }
        }
        int guard = 0;
        while (__hip_atomic_load(flags + l*16, __ATOMIC_RELAXED,
                                 __HIP_MEMORY_SCOPE_AGENT) == 0) {
            __builtin_amdgcn_s_sleep(2);
            if (++guard > (1 << 20)) break;            // fail-safe
        }
        __builtin_amdgcn_fence(__ATOMIC_ACQUIRE, "workgroup"); // compiler order
    }
    __syncthreads();
}

// GIN layer: hout = hin + mlp(hin + sum_nbr hin).
// phase2 thread=(n-quad, u): 4-node register reuse per weight load.
// phase3 thread=(n-pair, f): 2-node reuse. All weight streams 256B/wave.
template<bool LAST>
__device__ __forceinline__ void gin_layer(Shm& S, int base, int f32,
        const float* __restrict__ hin, float* hout,
        const void* Wa, const void* ba, const void* Wb, const void* bb,
        void* out)
{
    const int tid = threadIdx.x;
    // phase 1: m = own + sum of 15 neighbors (coalesced 256B rows)
    #pragma unroll
    for (int p = 0; p < 2; p++) {
        const int e = tid + p*256, n = e >> 6, f = e & 63, gi = base + n;
        const float own = hin[gi*LAT + f];
        float acc = own;
        #pragma unroll
        for (int k = 0; k < KNN; k++) acc += hin[S.snb[n*KNN + k]*LAT + f];
        S.u.g.m[e] = acc; S.u.g.own[e] = own;
    }
    __syncthreads();
    // phase 2: t[8][128] = relu(m @ Wa + ba); thread = (n2 = tid>>7, u = tid&127)
    {
        const int n2 = (tid >> 7) * 4, u = tid & 127;
        float a0 = ldf(ba, u, f32);
        float a1 = a0, a2 = a0, a3 = a0;
        if (f32) {
            const float* W = (const float*)Wa;
            #pragma unroll 8
            for (int f = 0; f < LAT; f++) {
                const float w = W[f*HID + u];
                a0 = fmaf(S.u.g.m[(n2    )*LAT + f], w, a0);
                a1 = fmaf(S.u.g.m[(n2 + 1)*LAT + f], w, a1);
                a2 = fmaf(S.u.g.m[(n2 + 2)*LAT + f], w, a2);
                a3 = fmaf(S.u.g.m[(n2 + 3)*LAT + f], w, a3);
            }
        } else {
            const bf16* W = (const bf16*)Wa;
            #pragma unroll 8
            for (int f = 0; f < LAT; f++) {
                const float w = bf2f(W[f*HID + u]);
                a0 = fmaf(S.u.g.m[(n2    )*LAT + f], w, a0);
                a1 = fmaf(S.u.g.m[(n2 + 1)*LAT + f], w, a1);
                a2 = fmaf(S.u.g.m[(n2 + 2)*LAT + f], w, a2);
                a3 = fmaf(S.u.g.m[(n2 + 3)*LAT + f], w, a3);
            }
        }
        S.u.g.t[(n2    )*HID + u] = a0 > 0.f ? a0 : 0.f;
        S.u.g.t[(n2 + 1)*HID + u] = a1 > 0.f ? a1 : 0.f;
        S.u.g.t[(n2 + 2)*HID + u] = a2 > 0.f ? a2 : 0.f;
        S.u.g.t[(n2 + 3)*HID + u] = a3 > 0.f ? a3 : 0.f;
    }
    __syncthreads();
    // phase 3: g[8][64] = t @ Wb + bb; thread = (q = tid>>6 -> nodes q,q+4; f)
    {
        const int q = tid >> 6, f = tid & 63;
        float a0 = ldf(bb, f, f32);
        float a1 = a0;
        if (f32) {
            const float* W = (const float*)Wb;
            #pragma unroll 8
            for (int u = 0; u < HID; u++) {
                const float w = W[u*LAT + f];
                a0 = fmaf(S.u.g.t[(q    )*HID + u], w, a0);
                a1 = fmaf(S.u.g.t[(q + 4)*HID + u], w, a1);
            }
        } else {
            const bf16* W = (const bf16*)Wb;
            #pragma unroll 8
            for (int u = 0; u < HID; u++) {
                const float w = bf2f(W[u*LAT + f]);
                a0 = fmaf(S.u.g.t[(q    )*HID + u], w, a0);
                a1 = fmaf(S.u.g.t[(q + 4)*HID + u], w, a1);
            }
        }
        const float o0 = S.u.g.own[(q    )*LAT + f] + a0;
        const float o1 = S.u.g.own[(q + 4)*LAT + f] + a1;
        const int gi0 = base + q, gi1 = base + q + 4;
        if (!LAST) {
            st_coh(&hout[gi0*LAT + f], o0);
            st_coh(&hout[gi1*LAT + f], o1);
        } else {
            S.sh[(q    )*LAT + f] = o0;
            S.sh[(q + 4)*LAT + f] = o1;
            if (f32) {
                ((float*)out)[gi0*LAT + f] = o0;        // output 0: final h
                ((float*)out)[gi1*LAT + f] = o1;
            } else {
                ((bf16*)out)[gi0*LAT + f] = f2bf(o0);
                ((bf16*)out)[gi1*LAT + f] = f2bf(o1);
            }
        }
    }
    __syncthreads();
}

__global__ __launch_bounds__(256, 4) void k_fused(KArgs a)
{
    __shared__ Shm S;
    const int tid = threadIdx.x, blk = blockIdx.x;
    const int base = blk * NPB;

    // ---- P0: dtype detect (16 KB scan of W_g1a; L2-hot)
    {
        int c = 0;
        for (int i = tid; i < 4096; i += 256) {
            const u32 x = a.wdet[i];
            c += ((x >> 7)  & 0xffu) >= 0xC8u;   // low half as bf16: |v| >= 2^73
            c += ((x >> 23) & 0xffu) >= 0xC8u;   // high half
        }
        S.u.red[tid] = c;
        __syncthreads();
        for (int s = 128; s > 0; s >>= 1) {
            if (tid < s) S.u.red[tid] += S.u.red[tid + s];
            __syncthreads();
        }
        if (tid == 0) S.flag = (S.u.red[0] > 64) ? 1 : 0;   // 1 = fp32 inputs
        __syncthreads();
    }
    const int f32 = S.flag;
    __syncthreads();

    // ---- P1: space_emb  h = leaky(x@W1+b1)@W2+b2
    {
        #pragma unroll
        for (int p = 0; p < 2; p++) {
            const int e = tid + p*256, n = e >> 6, f = e & 63, node = base + n;
            float acc = ldf(a.bse1, f, f32);
            #pragma unroll
            for (int i = 0; i < 4; i++)
                acc = fmaf(ldf(a.x, node*4 + i, f32), ldf(a.se1, i*LAT + f, f32), acc);
            acc = acc > 0.f ? acc : 0.01f*acc;              // leaky
            S.u.hid[n][f] = acc;
        }
        __syncthreads();
        // phase 2: thread = (q -> nodes q, q+4; f). 2-node weight reuse.
        const int q = tid >> 6, f = tid & 63;
        float a0 = ldf(a.bse2, f, f32);
        float a1 = a0;
        if (f32) {
            const float* W = (const float*)a.se2;
            #pragma unroll 8
            for (int j = 0; j < LAT; j++) {
                const float w = W[j*LAT + f];
                a0 = fmaf(S.u.hid[q][j],     w, a0);
                a1 = fmaf(S.u.hid[q + 4][j], w, a1);
            }
        } else {
            const bf16* W = (const bf16*)a.se2;
            #pragma unroll 8
            for (int j = 0; j < LAT; j++) {
                const float w = bf2f(W[j*LAT + f]);
                a0 = fmaf(S.u.hid[q][j],     w, a0);
                a1 = fmaf(S.u.hid[q + 4][j], w, a1);
            }
        }
        const int n0 = base + q, n1 = base + q + 4;
        st_coh(&a.hA[n0*LAT + f], a0);
        st_coh(&a.hA[n1*LAT + f], a1);
        if (f < 3) {
            st_coh(&a.pos[n0*3 + f], a0);
            st_coh(&a.pos[n1*3 + f], a1);
        }
    }
    gridbar(a.bar + BARA_LEAF/4, a.bar + BARA_ROOT/4, a.bar + BARA_FLAG/4);

    // ---- P2: kNN; one wave per node, 2 nodes per wave; nbr kept in LDS
    {
        const int eb = base & ~(NPE - 1);
        for (int i = tid; i < NPE*3; i += 256) S.u.kpos[i] = a.pos[(size_t)eb*3 + i];
        __syncthreads();
        const int wave = tid >> 6, lane = tid & 63;
        #pragma unroll
        for (int t = 0; t < 2; ++t) {
            const int n  = base + wave*2 + t;
            const int nl = n - eb;
            const float px = S.u.kpos[nl*3], py = S.u.kpos[nl*3+1], pz = S.u.kpos[nl*3+2];
            u64 key[4];
            #pragma unroll
            for (int c = 0; c < 4; c++) {
                const int j = 64*c + lane;
                const float dx = px - S.u.kpos[j*3], dy = py - S.u.kpos[j*3+1],
                            dz = pz - S.u.kpos[j*3+2];
                // match numpy fp32 ((x^2 + y^2) + z^2), contraction suppressed
                float dd = __fmul_rn(dx, dx);
                dd = __fadd_rn(dd, __fmul_rn(dy, dy));
                dd = __fadd_rn(dd, __fmul_rn(dz, dz));
                key[c] = ((u64)__float_as_uint(dd) << 32) | (u32)j;
                if (j == nl) key[c] = ~0ull;                 // exclude self
            }
            u64 lmin = key[0] < key[1] ? key[0] : key[1];
            { u64 q = key[2] < key[3] ? key[2] : key[3]; lmin = q < lmin ? q : lmin; }
            int myj = 0;                                     // lane k keeps k-th winner
            #pragma unroll
            for (int k = 0; k < KNN; k++) {
                u64 m = lmin;
                #pragma unroll
                for (int s = 32; s >= 1; s >>= 1) {          // butterfly min, 64 lanes
                    const u64 o = __shfl_xor(m, s, 64);
                    m = o < m ? o : m;
                }
                if (lane == k) myj = (int)(u32)m;
                #pragma unroll
                for (int c = 0; c < 4; c++) if (key[c] == m) key[c] = ~0ull;
                lmin = key[0] < key[1] ? key[0] : key[1];
                { u64 q = key[2] < key[3] ? key[2] : key[3]; lmin = q < lmin ? q : lmin; }
            }
            if (lane < KNN) {
                const int gj = eb + myj;
                S.snb[(n - base)*KNN + lane] = gj;
                if (f32) {
                    float* o = (float*)a.out;
                    o[EI0 + n*KNN + lane]      = (float)gj;  // output 2: ei
                    o[EI0 + NK + n*KNN + lane] = (float)n;
                } else {
                    bf16* o = (bf16*)a.out;
                    o[EI0 + n*KNN + lane]      = f2bf((float)gj);
                    o[EI0 + NK + n*KNN + lane] = f2bf((float)n);
                }
            }
        }
        __syncthreads();
    }

    // ---- P3: GIN layer 1 (hA -> hB, coherence-point stores)
    gin_layer<false>(S, base, f32, a.hA, a.hB,
                     a.g1a, a.bg1a, a.g1b, a.bg1b, nullptr);
    gridbar(a.bar + BARB_LEAF/4, a.bar + BARB_ROOT/4, a.bar + BARB_FLAG/4);

    // ---- P4: GIN layer 2 (hB -> LDS sh + d_out h)
    gin_layer<true>(S, base, f32, a.hB, nullptr,
                    a.g2a, a.bg2a, a.g2b, a.bg2b, a.out);

    // ---- P5: out_emb FFN from LDS sh (block-local)
    {
        const int q = tid >> 6, f = tid & 63;
        float a0 = ldf(a.boe1, f, f32);
        float a1 = a0;
        if (f32) {
            const float* W = (const float*)a.oe1;
            #pragma unroll 8
            for (int j = 0; j < LAT; j++) {
                const float w = W[j*LAT + f];
                a0 = fmaf(S.sh[(q    )*LAT + j], w, a0);
                a1 = fmaf(S.sh[(q + 4)*LAT + j], w, a1);
            }
        } else {
            const bf16* W = (const bf16*)a.oe1;
            #pragma unroll 8
            for (int j = 0; j < LAT; j++) {
                const float w = bf2f(W[j*LAT + f]);
                a0 = fmaf(S.sh[(q    )*LAT + j], w, a0);
                a1 = fmaf(S.sh[(q + 4)*LAT + j], w, a1);
            }
        }
        a0 = a0 > 0.f ? a0 : 0.01f*a0;                      // leaky
        a1 = a1 > 0.f ? a1 : 0.01f*a1;
        __syncthreads();                                     // S.u reuse (st)
        S.u.st[(q    )*LAT + f] = a0;
        S.u.st[(q + 4)*LAT + f] = a1;
        __syncthreads();
        if (tid < NPB*4) {
            const int n = tid >> 2, ff = tid & 3;
            float acc = ldf(a.boe2, ff, f32);
            for (int j = 0; j < LAT; j++)
                acc = fmaf(S.u.st[n*LAT + j], ldf(a.oe2, j*4 + ff, f32), acc);
            const int xo = N_NODES*LAT + (base + n)*4 + ff;  // output 1: x_emb
            if (f32) ((float*)a.out)[xo] = acc;
            else     ((bf16*)a.out)[xo] = f2bf(acc);
        }
    }
}

extern "C" void kernel_launch(void* const* d_in, const int* in_sizes, int n_in,
                              void* d_out, int out_size, void* d_ws, size_t ws_size,
                              hipStream_t stream)
{
    (void)in_sizes; (void)n_in; (void)out_size; (void)ws_size;
    char* ws = (char*)d_ws;

    KArgs a;
    a.x   = d_in[0];
    a.se1 = d_in[3];  a.bse1 = d_in[4];  a.se2 = d_in[5];  a.bse2 = d_in[6];
    a.g1a = d_in[7];  a.bg1a = d_in[8];  a.g1b = d_in[9];  a.bg1b = d_in[10];
    a.g2a = d_in[11]; a.bg2a = d_in[12]; a.g2b = d_in[13]; a.bg2b = d_in[14];
    a.oe1 = d_in[15]; a.boe1 = d_in[16]; a.oe2 = d_in[17]; a.boe2 = d_in[18];
    a.wdet = (const u32*)d_in[7];
    a.hA  = (float*)(ws + OFF_HA);
    a.hB  = (float*)(ws + OFF_HB);
    a.pos = (float*)(ws + OFF_POS);
    a.bar = (int*)ws;
    a.out = d_out;

    hipMemsetAsync(d_ws, 0, BAR_BYTES, stream);   // zero barrier tree (captured)
    k_fused<<<dim3(NBLK), dim3(256), 0, stream>>>(a);
}

// Round 4
// 152.581 us; speedup vs baseline: 2.3437x; 1.0527x over previous
//
#include <hip/hip_runtime.h>

// LevelLayer fully fused, one persistent kernel, 512 blocks x 512 thr
// (2 blocks/CU via ~21KB LDS + __launch_bounds__(512,4) => 16 waves/CU).
// Phases: detect -> space FFN -> [BAR A] -> kNN -> GIN1 -> [BAR B] ->
//         GIN2 -> out FFN.
// Cross-block data (pos/hA/hB) is written with AGENT-scope relaxed atomic
// stores (cache-bypassing, complete at coherence point) => grid barrier needs
// NO L2 writeback/invalidate fences. Readers use normal loads (lines never
// locally cached -> miss to coherence point, see fresh data).
// Barrier: 32-leaf(x16) + root counter tree, spread flag lines, relaxed poll.
// GIN phase-1 gather: 15 neighbor rows loaded into NAMED registers before
// summing -> 15 outstanding loads (round-3 version was load-add serialized at
// VGPR_Count=40).
// Outputs in d_out: h[8192*64] | x_emb[8192*4] | ei[2*122880].

#define N_NODES 8192
#define NPE     256
#define KNN     15
#define LAT     64
#define HID     128
#define NK      (N_NODES*KNN)
#define NBLK    512
#define NTHR    512
#define NPB     16
#define EI0     (N_NODES*LAT + N_NODES*4)

// barrier region (zeroed by hipMemsetAsync each launch)
#define BARA_LEAF 0
#define BARA_ROOT 2048
#define BARA_FLAG 4096
#define BARB_LEAF 8192
#define BARB_ROOT 10240
#define BARB_FLAG 12288
#define BAR_BYTES 16384

#define OFF_HA  BAR_BYTES
#define OFF_HB  (OFF_HA + N_NODES*LAT*4)
#define OFF_POS (OFF_HB + N_NODES*LAT*4)

typedef unsigned short bf16;
typedef unsigned int   u32;
typedef unsigned long long u64;

__device__ __forceinline__ float bf2f(bf16 s) {
    union { u32 u; float f; } v; v.u = ((u32)s) << 16; return v.f;
}
__device__ __forceinline__ bf16 f2bf(float f) {
    union { float f; u32 u; } v; v.f = f;
    u32 u = v.u + 0x7fffu + ((v.u >> 16) & 1u);   // RNE
    return (bf16)(u >> 16);
}
__device__ __forceinline__ float ldf(const void* p, int i, int f32) {
    return f32 ? ((const float*)p)[i] : bf2f(((const bf16*)p)[i]);
}
// agent-scope relaxed atomic store: bypasses local L1/L2, completes at the
// cross-XCD coherence point. vmcnt(0) after these == globally visible.
__device__ __forceinline__ void st_coh(float* p, float v) {
    __hip_atomic_store(p, v, __ATOMIC_RELAXED, __HIP_MEMORY_SCOPE_AGENT);
}

struct KArgs {
    const void* x;
    const void* se1; const void* bse1; const void* se2; const void* bse2;
    const void* g1a; const void* bg1a; const void* g1b; const void* bg1b;
    const void* g2a; const void* bg2a; const void* g2b; const void* bg2b;
    const void* oe1; const void* boe1; const void* oe2; const void* boe2;
    const u32* wdet;                 // d_in[7] = W_g1a raw bits
    float* hA; float* hB; float* pos; int* bar;
    void* out;
};

struct Shm {
    union {
        int   red[NTHR];                                       // detect
        float hid[NPB][LAT];                                   // space mid
        float kpos[NPE * 3];                                   // knn
        struct { float m[NPB*LAT]; float own[NPB*LAT]; float t[NPB*HID]; } g;  // 16 KB
        float st[NPB*LAT];                                     // out mid
    } u;                                                       // 16 KB
    int   snb[NPB*KNN];
    float sh[NPB*LAT];    // gin2 output, consumed by out FFN
    int   flag;
};                        // ~21.3 KB

// Fence-free tree grid barrier (512 arrivals: 32 leaves x 16 -> root).
// Bounded spin: broken co-residency -> clean wrong answer, never a hang.
__device__ __forceinline__ void gridbar(int* leaf, int* root, int* flags) {
    asm volatile("s_waitcnt vmcnt(0)" ::: "memory");   // all waves: stores acked
    __syncthreads();
    if (threadIdx.x == 0) {
        const int l = blockIdx.x & 31;
        if (__hip_atomic_fetch_add(leaf + l*16, 1, __ATOMIC_RELAXED,
                                   __HIP_MEMORY_SCOPE_AGENT) == 15) {
            if (__hip_atomic_fetch_add(root, 1, __ATOMIC_RELAXED,
                                       __HIP_MEMORY_SCOPE_AGENT) == 31) {
                #pragma unroll
                for (int i = 0; i < 32; i++)
                    __hip_atomic_store(flags + i*16, 1, __ATOMIC_RELAXED,
                                       __HIP_MEMORY_SCOPE_AGENT);
            }
        }
        int guard = 0;
        while (__hip_atomic_load(flags + l*16, __ATOMIC_RELAXED,
                                 __HIP_MEMORY_SCOPE_AGENT) == 0) {
            __builtin_amdgcn_s_sleep(2);
            if (++guard > (1 << 20)) break;            // fail-safe
        }
        __builtin_amdgcn_fence(__ATOMIC_ACQUIRE, "workgroup"); // compiler order
    }
    __syncthreads();
}

// GIN layer: hout = hin + mlp(hin + sum_nbr hin).  NPB=16 nodes/block.
// phase1: 15 rows loaded to named regs (15 outstanding loads) then summed.
// phase2 thread=(n-quad, u): 4-node register reuse per weight load.
// phase3 thread=(n-pair, f): 2-node reuse. Weight streams 128-256B/wave.
template<bool LAST>
__device__ __forceinline__ void gin_layer(Shm& S, int base, int f32,
        const float* __restrict__ hin, float* hout,
        const void* Wa, const void* ba, const void* Wb, const void* bb,
        void* out)
{
    const int tid = threadIdx.x;
    // phase 1: m = own + sum of 15 neighbors (wave-uniform rows, 256B loads)
    #pragma unroll
    for (int p = 0; p < 2; p++) {
        const int e = tid + p*NTHR, n = e >> 6, f = e & 63, gi = base + n;
        const int* nb = &S.snb[n*KNN];
        const float own = hin[gi*LAT + f];
        float vv[KNN];
        #pragma unroll
        for (int k = 0; k < KNN; k++) vv[k] = hin[nb[k]*LAT + f];
        float s0 = vv[0] + vv[1],  s1 = vv[2]  + vv[3],  s2 = vv[4]  + vv[5];
        float s3 = vv[6] + vv[7],  s4 = vv[8]  + vv[9],  s5 = vv[10] + vv[11];
        float s6 = vv[12] + vv[13];
        const float acc = own + (((s0 + s1) + (s2 + s3)) + ((s4 + s5) + (s6 + vv[14])));
        S.u.g.m[e] = acc; S.u.g.own[e] = own;
    }
    __syncthreads();
    // phase 2: t[16][128] = relu(m @ Wa + ba); thread = (n4 = (tid>>7)*4, u = tid&127)
    {
        const int n4 = (tid >> 7) * 4, u = tid & 127;
        float a0 = ldf(ba, u, f32);
        float a1 = a0, a2 = a0, a3 = a0;
        if (f32) {
            const float* W = (const float*)Wa;
            #pragma unroll 8
            for (int f = 0; f < LAT; f++) {
                const float w = W[f*HID + u];
                a0 = fmaf(S.u.g.m[(n4    )*LAT + f], w, a0);
                a1 = fmaf(S.u.g.m[(n4 + 1)*LAT + f], w, a1);
                a2 = fmaf(S.u.g.m[(n4 + 2)*LAT + f], w, a2);
                a3 = fmaf(S.u.g.m[(n4 + 3)*LAT + f], w, a3);
            }
        } else {
            const bf16* W = (const bf16*)Wa;
            #pragma unroll 8
            for (int f = 0; f < LAT; f++) {
                const float w = bf2f(W[f*HID + u]);
                a0 = fmaf(S.u.g.m[(n4    )*LAT + f], w, a0);
                a1 = fmaf(S.u.g.m[(n4 + 1)*LAT + f], w, a1);
                a2 = fmaf(S.u.g.m[(n4 + 2)*LAT + f], w, a2);
                a3 = fmaf(S.u.g.m[(n4 + 3)*LAT + f], w, a3);
            }
        }
        S.u.g.t[(n4    )*HID + u] = a0 > 0.f ? a0 : 0.f;
        S.u.g.t[(n4 + 1)*HID + u] = a1 > 0.f ? a1 : 0.f;
        S.u.g.t[(n4 + 2)*HID + u] = a2 > 0.f ? a2 : 0.f;
        S.u.g.t[(n4 + 3)*HID + u] = a3 > 0.f ? a3 : 0.f;
    }
    __syncthreads();
    // phase 3: g[16][64] = t @ Wb + bb; thread = (q = tid>>6 -> nodes q,q+8; f)
    {
        const int q = tid >> 6, f = tid & 63;
        float a0 = ldf(bb, f, f32);
        float a1 = a0;
        if (f32) {
            const float* W = (const float*)Wb;
            #pragma unroll 8
            for (int u = 0; u < HID; u++) {
                const float w = W[u*LAT + f];
                a0 = fmaf(S.u.g.t[(q    )*HID + u], w, a0);
                a1 = fmaf(S.u.g.t[(q + 8)*HID + u], w, a1);
            }
        } else {
            const bf16* W = (const bf16*)Wb;
            #pragma unroll 8
            for (int u = 0; u < HID; u++) {
                const float w = bf2f(W[u*LAT + f]);
                a0 = fmaf(S.u.g.t[(q    )*HID + u], w, a0);
                a1 = fmaf(S.u.g.t[(q + 8)*HID + u], w, a1);
            }
        }
        const float o0 = S.u.g.own[(q    )*LAT + f] + a0;
        const float o1 = S.u.g.own[(q + 8)*LAT + f] + a1;
        const int gi0 = base + q, gi1 = base + q + 8;
        if (!LAST) {
            st_coh(&hout[gi0*LAT + f], o0);
            st_coh(&hout[gi1*LAT + f], o1);
        } else {
            S.sh[(q    )*LAT + f] = o0;
            S.sh[(q + 8)*LAT + f] = o1;
            if (f32) {
                ((float*)out)[gi0*LAT + f] = o0;        // output 0: final h
                ((float*)out)[gi1*LAT + f] = o1;
            } else {
                ((bf16*)out)[gi0*LAT + f] = f2bf(o0);
                ((bf16*)out)[gi1*LAT + f] = f2bf(o1);
            }
        }
    }
    __syncthreads();
}

__global__ __launch_bounds__(NTHR, 4) void k_fused(KArgs a)
{
    __shared__ Shm S;
    const int tid = threadIdx.x, blk = blockIdx.x;
    const int base = blk * NPB;

    // ---- P0: dtype detect (16 KB scan of W_g1a; L2-hot)
    {
        int c = 0;
        for (int i = tid; i < 4096; i += NTHR) {
            const u32 x = a.wdet[i];
            c += ((x >> 7)  & 0xffu) >= 0xC8u;   // low half as bf16: |v| >= 2^73
            c += ((x >> 23) & 0xffu) >= 0xC8u;   // high half
        }
        S.u.red[tid] = c;
        __syncthreads();
        for (int s = NTHR/2; s > 0; s >>= 1) {
            if (tid < s) S.u.red[tid] += S.u.red[tid + s];
            __syncthreads();
        }
        if (tid == 0) S.flag = (S.u.red[0] > 64) ? 1 : 0;   // 1 = fp32 inputs
        __syncthreads();
    }
    const int f32 = S.flag;
    __syncthreads();

    // ---- P1: space_emb  h = leaky(x@W1+b1)@W2+b2
    {
        #pragma unroll
        for (int p = 0; p < 2; p++) {
            const int e = tid + p*NTHR, n = e >> 6, f = e & 63, node = base + n;
            float acc = ldf(a.bse1, f, f32);
            #pragma unroll
            for (int i = 0; i < 4; i++)
                acc = fmaf(ldf(a.x, node*4 + i, f32), ldf(a.se1, i*LAT + f, f32), acc);
            acc = acc > 0.f ? acc : 0.01f*acc;              // leaky
            S.u.hid[n][f] = acc;
        }
        __syncthreads();
        // phase 2: thread = (q -> nodes q, q+8; f). 2-node weight reuse.
        const int q = tid >> 6, f = tid & 63;
        float a0 = ldf(a.bse2, f, f32);
        float a1 = a0;
        if (f32) {
            const float* W = (const float*)a.se2;
            #pragma unroll 8
            for (int j = 0; j < LAT; j++) {
                const float w = W[j*LAT + f];
                a0 = fmaf(S.u.hid[q][j],     w, a0);
                a1 = fmaf(S.u.hid[q + 8][j], w, a1);
            }
        } else {
            const bf16* W = (const bf16*)a.se2;
            #pragma unroll 8
            for (int j = 0; j < LAT; j++) {
                const float w = bf2f(W[j*LAT + f]);
                a0 = fmaf(S.u.hid[q][j],     w, a0);
                a1 = fmaf(S.u.hid[q + 8][j], w, a1);
            }
        }
        const int n0 = base + q, n1 = base + q + 8;
        st_coh(&a.hA[n0*LAT + f], a0);
        st_coh(&a.hA[n1*LAT + f], a1);
        if (f < 3) {
            st_coh(&a.pos[n0*3 + f], a0);
            st_coh(&a.pos[n1*3 + f], a1);
        }
    }
    gridbar(a.bar + BARA_LEAF/4, a.bar + BARA_ROOT/4, a.bar + BARA_FLAG/4);

    // ---- P2: kNN; one wave per node, 2 nodes per wave; nbr kept in LDS
    {
        const int eb = base & ~(NPE - 1);
        for (int i = tid; i < NPE*3; i += NTHR) S.u.kpos[i] = a.pos[(size_t)eb*3 + i];
        __syncthreads();
        const int wave = tid >> 6, lane = tid & 63;
        #pragma unroll
        for (int t = 0; t < 2; ++t) {
            const int n  = base + wave*2 + t;
            const int nl = n - eb;
            const float px = S.u.kpos[nl*3], py = S.u.kpos[nl*3+1], pz = S.u.kpos[nl*3+2];
            u64 key[4];
            #pragma unroll
            for (int c = 0; c < 4; c++) {
                const int j = 64*c + lane;
                const float dx = px - S.u.kpos[j*3], dy = py - S.u.kpos[j*3+1],
                            dz = pz - S.u.kpos[j*3+2];
                // match numpy fp32 ((x^2 + y^2) + z^2), contraction suppressed
                float dd = __fmul_rn(dx, dx);
                dd = __fadd_rn(dd, __fmul_rn(dy, dy));
                dd = __fadd_rn(dd, __fmul_rn(dz, dz));
                key[c] = ((u64)__float_as_uint(dd) << 32) | (u32)j;
                if (j == nl) key[c] = ~0ull;                 // exclude self
            }
            // sort 4 candidates ascending: (0,1)(2,3)(0,2)(1,3)(1,2)
            #define CSWAP(A,B) { const u64 x_ = key[A], y_ = key[B]; \
                                 key[A] = x_ < y_ ? x_ : y_; key[B] = x_ < y_ ? y_ : x_; }
            CSWAP(0,1) CSWAP(2,3) CSWAP(0,2) CSWAP(1,3) CSWAP(1,2)
            #undef CSWAP
            int myj = 0;                                     // lane k keeps k-th winner
            #pragma unroll
            for (int k = 0; k < KNN; k++) {
                u64 m = key[0];                              // lane-sorted: head is min
                #pragma unroll
                for (int s = 32; s >= 1; s >>= 1) {          // butterfly min, 64 lanes
                    const u64 o = __shfl_xor(m, s, 64);
                    m = o < m ? o : m;
                }
                if (lane == k) myj = (int)(u32)m;
                const bool hit = (key[0] == m);              // unique j => one holder
                key[0] = hit ? key[1] : key[0];              // pop
                key[1] = hit ? key[2] : key[1];
                key[2] = hit ? key[3] : key[2];
                key[3] = hit ? ~0ull  : key[3];
            }
            if (lane < KNN) {
                const int gj = eb + myj;
                S.snb[(n - base)*KNN + lane] = gj;
                if (f32) {
                    float* o = (float*)a.out;
                    o[EI0 + n*KNN + lane]      = (float)gj;  // output 2: ei
                    o[EI0 + NK + n*KNN + lane] = (float)n;
                } else {
                    bf16* o = (bf16*)a.out;
                    o[EI0 + n*KNN + lane]      = f2bf((float)gj);
                    o[EI0 + NK + n*KNN + lane] = f2bf((float)n);
                }
            }
        }
        __syncthreads();
    }

    // ---- P3: GIN layer 1 (hA -> hB, coherence-point stores)
    gin_layer<false>(S, base, f32, a.hA, a.hB,
                     a.g1a, a.bg1a, a.g1b, a.bg1b, nullptr);
    gridbar(a.bar + BARB_LEAF/4, a.bar + BARB_ROOT/4, a.bar + BARB_FLAG/4);

    // ---- P4: GIN layer 2 (hB -> LDS sh + d_out h)
    gin_layer<true>(S, base, f32, a.hB, nullptr,
                    a.g2a, a.bg2a, a.g2b, a.bg2b, a.out);

    // ---- P5: out_emb FFN from LDS sh (block-local)
    {
        const int q = tid >> 6, f = tid & 63;
        float a0 = ldf(a.boe1, f, f32);
        float a1 = a0;
        if (f32) {
            const float* W = (const float*)a.oe1;
            #pragma unroll 8
            for (int j = 0; j < LAT; j++) {
                const float w = W[j*LAT + f];
                a0 = fmaf(S.sh[(q    )*LAT + j], w, a0);
                a1 = fmaf(S.sh[(q + 8)*LAT + j], w, a1);
            }
        } else {
            const bf16* W = (const bf16*)a.oe1;
            #pragma unroll 8
            for (int j = 0; j < LAT; j++) {
                const float w = bf2f(W[j*LAT + f]);
                a0 = fmaf(S.sh[(q    )*LAT + j], w, a0);
                a1 = fmaf(S.sh[(q + 8)*LAT + j], w, a1);
            }
        }
        a0 = a0 > 0.f ? a0 : 0.01f*a0;                      // leaky
        a1 = a1 > 0.f ? a1 : 0.01f*a1;
        __syncthreads();                                     // S.u reuse (st)
        S.u.st[(q    )*LAT + f] = a0;
        S.u.st[(q + 8)*LAT + f] = a1;
        __syncthreads();
        if (tid < NPB*4) {
            const int n = tid >> 2, ff = tid & 3;
            float acc = ldf(a.boe2, ff, f32);
            for (int j = 0; j < LAT; j++)
                acc = fmaf(S.u.st[n*LAT + j], ldf(a.oe2, j*4 + ff, f32), acc);
            const int xo = N_NODES*LAT + (base + n)*4 + ff;  // output 1: x_emb
            if (f32) ((float*)a.out)[xo] = acc;
            else     ((bf16*)a.out)[xo] = f2bf(acc);
        }
    }
}

extern "C" void kernel_launch(void* const* d_in, const int* in_sizes, int n_in,
                              void* d_out, int out_size, void* d_ws, size_t ws_size,
                              hipStream_t stream)
{
    (void)in_sizes; (void)n_in; (void)out_size; (void)ws_size;
    char* ws = (char*)d_ws;

    KArgs a;
    a.x   = d_in[0];
    a.se1 = d_in[3];  a.bse1 = d_in[4];  a.se2 = d_in[5];  a.bse2 = d_in[6];
    a.g1a = d_in[7];  a.bg1a = d_in[8];  a.g1b = d_in[9];  a.bg1b = d_in[10];
    a.g2a = d_in[11]; a.bg2a = d_in[12]; a.g2b = d_in[13]; a.bg2b = d_in[14];
    a.oe1 = d_in[15]; a.boe1 = d_in[16]; a.oe2 = d_in[17]; a.boe2 = d_in[18];
    a.wdet = (const u32*)d_in[7];
    a.hA  = (float*)(ws + OFF_HA);
    a.hB  = (float*)(ws + OFF_HB);
    a.pos = (float*)(ws + OFF_POS);
    a.bar = (int*)ws;
    a.out = d_out;

    hipMemsetAsync(d_ws, 0, BAR_BYTES, stream);   // zero barrier tree (captured)
    k_fused<<<dim3(NBLK), dim3(NTHR), 0, stream>>>(a);
}